// Round 9
// baseline (124.046 us; speedup 1.0000x reference)
//
#include <hip/hip_runtime.h>
#include <stdint.h>

typedef float v4f __attribute__((ext_vector_type(4)));
typedef float f2u __attribute__((ext_vector_type(2), aligned(4)));  // 4B-aligned float2

#define PEX_STRIDE 1156
#define CSTRIDE 858   // u64 per shifted copy
#define WS_IMG8   0
#define WS_BFRAG  1048576
#define WS_PEX    1064960
#define WS_RB     5799936
#define WS_RESULT 9994240
#define WS_CAND   14188544
// within WS_CAND block: cnt@+0, done@+8, tilemax@+1024 (512 f32), cand@+4096

__device__ inline unsigned char f32_to_e4m3(float v) {
    if (!(v > 0.0f)) return 0;
    if (v >= 448.0f) return 0x7e;
    if (v < 0.015625f) {                       // subnormal: m * 2^-9
        int m = (int)(v * 512.0f + 0.5f);
        if (m > 7) return 0x08;
        return (unsigned char)m;
    }
    unsigned int u = __float_as_uint(v) + 0x00080000u;  // round into bit 20
    int e = (int)((u >> 23) & 0xff) - 127;
    int m3 = (int)(u >> 20) & 7;
    int e8 = e + 7;
    if (e8 >= 16) return 0x7e;
    return (unsigned char)((e8 << 3) | m3);
}

// Fused front kernel.
// blocks [0,1024): wrapped row prefix sums + fp8 image emit (row L1-hot)
// blocks [1024,2080): zero d_out
// blocks [2080,2144): A-fragment psf table + zero counters
__global__ void k_pex(const float* __restrict__ img, float* __restrict__ pex,
                      uint32_t* __restrict__ img8, const float* __restrict__ psf,
                      unsigned char* __restrict__ bf, unsigned int* cnt,
                      float4* __restrict__ out, int n4) {
    __shared__ float wtot[4];
    int blk = blockIdx.x, t = threadIdx.x;
    if (blk >= 1024) {
        if (blk < 2080) {
            int i = (blk - 1024) * 256 + t;
            if (i < n4) { float4 z; z.x = z.y = z.z = z.w = 0.f; out[i] = z; }
        } else {
            int u = (blk - 2080) * 256 + t;   // 16384
            if (u == 0) { cnt[0] = 0u; cnt[2] = 0u; }   // cnt, done
            int kb = u >> 9; int l = (u >> 3) & 63; int j = u & 7;
            int z = l & 15; int q = l >> 4;
            int a = kb; int b = q * 8 + j;
            float p = psf[z * 1024 + a * 32 + b];
            float c = cosf((float)(a + b - 32) * (6.283185307179586f / 1024.0f));
            bf[kb * 512 + l * 8 + j] = f32_to_e4m3(p * c * 1024.0f);
        }
        return;
    }
    int r = blk;
    const float* row = img + r * 1024;
    float s[5];
    float acc = 0.f;
    int base = t * 5;
    #pragma unroll
    for (int j = 0; j < 5; j++) {
        int c = base + j;
        float v = (c < 1152) ? row[(c - 64) & 1023] : 0.f;
        acc += v; s[j] = acc;
    }
    float sc = acc;
    int lane = t & 63, w = t >> 6;
    #pragma unroll
    for (int off = 1; off < 64; off <<= 1) {
        float v = __shfl_up(sc, off, 64);
        if (lane >= off) sc += v;
    }
    if (lane == 63) wtot[w] = sc;
    __syncthreads();
    float wbase = 0.f;
    #pragma unroll
    for (int i = 0; i < 3; i++) if (i < w) wbase += wtot[i];
    float excl = wbase + (sc - acc);
    float* prow = pex + r * PEX_STRIDE;
    if (t == 0) prow[0] = 0.f;
    #pragma unroll
    for (int j = 0; j < 5; j++) {
        int c = base + j;
        if (c < 1152) prow[c + 1] = excl + s[j];
    }
    float4 v4 = *(const float4*)(row + 4 * t);
    img8[r * 256 + t] = (uint32_t)f32_to_e4m3(v4.x)
                      | ((uint32_t)f32_to_e4m3(v4.y) << 8)
                      | ((uint32_t)f32_to_e4m3(v4.z) << 16)
                      | ((uint32_t)f32_to_e4m3(v4.w) << 24);
}

// exact disk(r=64) mean via prefix sums, sampled every 16th row; compact output
// rb[s][c] covers rows [16s,16s+16). XCD-banded mapping keeps pex L2-local.
__global__ __launch_bounds__(256) void k_bg(const float* __restrict__ pex,
                                            float* __restrict__ rb) {
    static constexpr int W[64] = {
        63,63,63,63,63,63,63,63,63,63,63,63,
        62,62,62,62, 61,61,61,61, 60,60,60, 59,59, 58,58,58, 57,57, 56,
        55,55, 54,54, 53, 52,52, 51, 50, 49,49,
        48,47,46,45,44,43,42,41,
        39,38,37,35,34,32,30,29,27,24,22,19,15,11
    };
    int blk = blockIdx.x;                 // 128
    int xcd = blk & 7;
    int sub = blk >> 4;                   // 0..7
    int half = (blk >> 3) & 1;
    int s = xcd * 8 + sub;                // sampled-row index 0..63
    int row = s * 16 + 7;
    int n0 = (half << 9) + ((int)threadIdx.x << 1);
    f2u acc0, acc1;
    {
        const float* pr = pex + row * PEX_STRIDE + n0;
        acc0 = *(const f2u*)(pr + 128) - *(const f2u*)(pr + 1);
        acc1 = (f2u)0.f;
    }
    #pragma unroll 3
    for (int dy = 1; dy <= 63; dy++) {
        const int w = W[dy];
        const float* p1 = pex + ((row - dy) & 1023) * PEX_STRIDE + n0;
        const float* p2 = pex + ((row + dy) & 1023) * PEX_STRIDE + n0;
        acc0 += *(const f2u*)(p1 + 65 + w) - *(const f2u*)(p1 + 64 - w);
        acc1 += *(const f2u*)(p2 + 65 + w) - *(const f2u*)(p2 + 64 - w);
    }
    f2u sum = acc0 + acc1;
    const float k = (float)(1.0 / (3.14159265358979323846 * 4096.0));
    f2u r2;
    r2.x = 1.0f / ((sum.x * k + 1.0f) * 1024.0f);   // /1024 undoes psf scale
    r2.y = 1.0f / ((sum.y * k + 1.0f) * 1024.0f);
    *(f2u*)(rb + s * 1024 + n0) = r2;
}

// MFMA conv, swapped operands, Toeplitz register pipeline in TWO PASSES of 8
// output rows each: per pass acc[8] (32 VGPR) + breg[8] window (16 VGPR) ->
// peak ~90 VGPR, cap 128 via __launch_bounds__(512,4) => 2 blocks/CU.
// One ds_read_b64 refill per kb per pass (8x less LDS traffic than R6).
__global__ __launch_bounds__(512, 4) void k_conv(
    const unsigned long long* __restrict__ img64,
    const unsigned long long* __restrict__ bfrag,
    const float* __restrict__ rb, float* __restrict__ result,
    float* __restrict__ tilemax) {
    __shared__ unsigned long long sm[8 * CSTRIDE];   // 54912 B
    __shared__ float bmax[8];
    int tid = threadIdx.x;
    int wave = tid >> 6, lane = tid & 63;
    int b = blockIdx.x;
    int tr = b >> 5, tc = b & 31;
    int r0 = tr * 64, c0 = tc * 32;

    for (int u = tid; u < 665; u += 512) {    // 95 rows x 7 slots
        int dr = u / 7;
        int x8 = u - dr * 7;
        int row = (r0 + dr - 16) & 1023;
        int cb0 = (c0 + x8 * 8 - 16) & 1023;
        int cb1 = (cb0 + 8) & 1023;
        unsigned long long lo = img64[row * 128 + (cb0 >> 3)];
        unsigned long long hi = img64[row * 128 + (cb1 >> 3)];
        int dst = dr * 9 + x8;
        sm[dst] = lo;
        #pragma unroll
        for (int s = 1; s < 8; s++)
            sm[s * CSTRIDE + dst] = (lo >> (8 * s)) | (hi << (64 - 8 * s));
    }
    __syncthreads();

    int i0 = (wave >> 1) * 16;                // tile row group
    int cw = (wave & 1) * 16;                 // col half
    int g = lane >> 4;
    int slot = ((cw + (lane & 15)) >> 3) + g;
    const unsigned long long* bp = sm + (lane & 7) * CSTRIDE + slot + i0 * 9;
    int gcol = c0 + cw + (lane & 15);
    float pm = -3.4e38f;

    #pragma unroll
    for (int h = 0; h < 2; h++) {             // output rows i0+8h .. i0+8h+7
        const unsigned long long* bph = bp + h * 72;   // +8*9
        unsigned long long breg[8];
        #pragma unroll
        for (int j = 0; j < 8; j++) breg[j] = bph[j * 9];
        v4f acc[8];
        #pragma unroll
        for (int f = 0; f < 8; f++) acc[f] = (v4f)0.0f;

        unsigned long long anext = bfrag[lane];
        #pragma unroll
        for (int kb = 0; kb < 32; kb++) {
            unsigned long long acur = anext;
            anext = bfrag[((kb < 31 ? kb + 1 : 31) << 6) + lane];
            #pragma unroll
            for (int j = 0; j < 8; j++) {
                acc[j] = __builtin_amdgcn_mfma_f32_16x16x32_fp8_fp8(
                    (long)acur, (long)breg[(kb + j) & 7], acc[j], 0, 0, 0);
            }
            // refill window slot with s_rel = kb+8 (abs s = kb+8+8h <= 46)
            int srel = (h == 0) ? (kb + 8) : (kb < 31 ? kb + 8 : 38);
            breg[kb & 7] = bph[srel * 9];
        }

        // epilogue: z-max in registers (C rows = z), wave-wide
        float zx[8];
        #pragma unroll
        for (int j = 0; j < 8; j++) {
            v4f v = acc[j];
            float m = fmaxf(fmaxf(v.x, v.y), fmaxf(v.z, v.w));
            m = fmaxf(m, __shfl_xor(m, 16, 64));
            m = fmaxf(m, __shfl_xor(m, 32, 64));
            zx[j] = m;
        }
        #pragma unroll
        for (int c2 = 0; c2 < 2; c2++) {
            float m01 = (g & 1) ? zx[c2 * 4 + 1] : zx[c2 * 4 + 0];
            float m23 = (g & 1) ? zx[c2 * 4 + 3] : zx[c2 * 4 + 2];
            float m = (g & 2) ? m23 : m01;
            int grow = r0 + i0 + h * 8 + c2 * 4 + g;
            float val = m * rb[(grow >> 4) * 1024 + gcol];
            result[grow * 1024 + gcol] = val;
            pm = fmaxf(pm, val);
        }
    }

    #pragma unroll
    for (int d = 1; d < 64; d <<= 1) pm = fmaxf(pm, __shfl_xor(pm, d, 64));
    if (lane == 0) bmax[wave] = pm;
    __syncthreads();
    if (tid == 0) {
        float m = bmax[0];
        #pragma unroll
        for (int i = 1; i < 8; i++) m = fmaxf(m, bmax[i]);
        tilemax[b] = m;
    }
}

// fused maxpool + candidate extraction + (last block) top-k sort & emit.
// Fast reject reads the 2 conv-tile maxes covering this 64x64 region.
__global__ __launch_bounds__(256) void k_maxcand(
    const float* __restrict__ result, const float* __restrict__ tilemax,
    unsigned int* cnt, unsigned long long* cand,
    const float* __restrict__ image, float* __restrict__ out) {
    __shared__ __align__(16) char smbuf[61184];   // ls | hr, aliased keys
    __shared__ unsigned int lastv;
    float* ls = (float*)smbuf;                    // 95*96*4 = 36480
    float* hr = (float*)(smbuf + 36480);          // 95*64*4 = 24320
    unsigned long long* keys = (unsigned long long*)smbuf;  // 16384 (aliased)
    int b = blockIdx.x;                            // 256
    int bx = b & 15, by = b >> 4;
    int i0 = by * 64, j0 = bx * 64;
    int t = threadIdx.x;
    unsigned int* done = cnt + 2;

    float tm = fmaxf(tilemax[by * 32 + 2 * bx], tilemax[by * 32 + 2 * bx + 1]);
    if (tm > 2.0f) {
        // slow path: full separable pooling on the 95x95 halo
        for (int idx = t; idx < 95 * 95; idx += 256) {
            int r = idx / 95, c = idx - r * 95;
            int gr = i0 - 16 + r, gc = j0 - 16 + c;
            float v = -3.4e38f;
            if ((unsigned)gr < 1024u && (unsigned)gc < 1024u) v = result[gr * 1024 + gc];
            ls[r * 96 + c] = v;
        }
        __syncthreads();
        for (int idx = t; idx < 95 * 64; idx += 256) {
            int r = idx >> 6, c = idx & 63;
            const float* p = ls + r * 96 + c;
            float m = p[0];
            #pragma unroll
            for (int d = 1; d < 32; d++) m = fmaxf(m, p[d]);
            hr[idx] = m;
        }
        __syncthreads();
        for (int idx = t; idx < 64 * 64; idx += 256) {
            int r = idx >> 6, c = idx & 63;
            const float* p = hr + r * 64 + c;
            float m = p[0];
            #pragma unroll
            for (int d = 1; d < 32; d++) m = fmaxf(m, p[d * 64]);
            float v = ls[(r + 16) * 96 + (c + 16)];
            int gi = i0 + r, gj = j0 + c;
            if (gi >= 1 && gj >= 1 && v > 2.0f && v == m) {
                unsigned int k = atomicAdd(cnt, 1u);
                if (k < 2048)
                    cand[k] = ((unsigned long long)__float_as_uint(v) << 32)
                            | (unsigned int)(~(unsigned int)(gi * 1024 + gj));
            }
        }
        __syncthreads();
    }

    // last-block election
    __threadfence();
    if (t == 0) lastv = atomicAdd(done, 1u);
    __syncthreads();
    if (lastv != 255) return;
    __threadfence();

    int n = (int)cnt[0]; if (n > 2048) n = 2048;
    if (n == 0) return;                           // d_out already zeroed
    for (int k = t; k < 2048; k += 256) keys[k] = (k < n) ? cand[k] : 0ull;
    __syncthreads();
    for (int size = 2; size <= 2048; size <<= 1) {
        for (int stride = size >> 1; stride > 0; stride >>= 1) {
            for (int i = t; i < 2048; i += 256) {
                int ixj = i ^ stride;
                if (ixj > i) {
                    unsigned long long a = keys[i], bb = keys[ixj];
                    bool sw = ((i & size) == 0) ? (a < bb) : (a > bb);  // descending
                    if (sw) { keys[i] = bb; keys[ixj] = a; }
                }
            }
            __syncthreads();
        }
    }
    float* roipos = out;
    float* intensity = out + 2048;
    float* rois = out + 3072;
    float* validf = out + 3072 + 1048576;
    int nw = n < 1024 ? n : 1024;
    for (int k = t; k < nw; k += 256) {
        unsigned long long key = keys[k];
        float val = __uint_as_float((unsigned int)(key >> 32));
        unsigned int p = ~(unsigned int)key;
        int y = (int)(p >> 10), x = (int)(p & 1023);
        int roy = y - 16, rox = x - 16;
        bool valid = (roy >= 0 && roy < 992 && rox >= 0 && rox < 992);
        int royc = roy < 0 ? 0 : (roy > 992 ? 992 : roy);
        int roxc = rox < 0 ? 0 : (rox > 992 ? 992 : rox);
        roipos[2 * k]     = valid ? (float)royc : 0.f;
        roipos[2 * k + 1] = valid ? (float)roxc : 0.f;
        intensity[k]      = valid ? val : 0.f;
        validf[k]         = valid ? 1.f : 0.f;
    }
    __syncthreads();
    for (int k = 0; k < nw; k++) {
        unsigned long long key = keys[k];
        unsigned int p = ~(unsigned int)key;
        int y = (int)(p >> 10), x = (int)(p & 1023);
        int roy = y - 16, rox = x - 16;
        if (!(roy >= 0 && roy < 992 && rox >= 0 && rox < 992)) continue;
        #pragma unroll
        for (int part = 0; part < 4; part++) {
            int tt = part * 256 + t;
            int u = tt >> 5, vv = tt & 31;
            rois[k * 1024 + tt] = image[(roy + u) * 1024 + (rox + vv)];
        }
    }
}

extern "C" void kernel_launch(void* const* d_in, const int* in_sizes, int n_in,
                              void* d_out, int out_size, void* d_ws, size_t ws_size,
                              hipStream_t stream) {
    const float* image = (const float*)d_in[0];
    const float* psf   = (const float*)d_in[1];
    float* out = (float*)d_out;
    char* ws = (char*)d_ws;
    unsigned char* img8  = (unsigned char*)(ws + WS_IMG8);
    unsigned char* bfrag = (unsigned char*)(ws + WS_BFRAG);
    float* pex = (float*)(ws + WS_PEX);
    float* rb  = (float*)(ws + WS_RB);
    float* result = (float*)(ws + WS_RESULT);
    unsigned int* cnt = (unsigned int*)(ws + WS_CAND);
    float* tilemax = (float*)(ws + WS_CAND + 1024);
    unsigned long long* cand = (unsigned long long*)(ws + WS_CAND + 4096);

    int n4 = out_size / 4;
    hipLaunchKernelGGL(k_pex,     dim3(2144), dim3(256), 0, stream,
                       image, pex, (uint32_t*)img8, psf, bfrag, cnt, (float4*)d_out, n4);
    hipLaunchKernelGGL(k_bg,      dim3(128),  dim3(256), 0, stream, pex, rb);
    hipLaunchKernelGGL(k_conv,    dim3(512),  dim3(512), 0, stream,
                       (const unsigned long long*)img8, (const unsigned long long*)bfrag,
                       rb, result, tilemax);
    hipLaunchKernelGGL(k_maxcand, dim3(256),  dim3(256), 0, stream,
                       result, tilemax, cnt, cand, image, out);
}

// Round 10
// 116.534 us; speedup vs baseline: 1.0645x; 1.0645x over previous
//
#include <hip/hip_runtime.h>
#include <stdint.h>

typedef float v4f __attribute__((ext_vector_type(4)));
typedef float f2u __attribute__((ext_vector_type(2), aligned(4)));  // 4B-aligned float2
typedef unsigned long long ull2 __attribute__((ext_vector_type(2), aligned(8)));

#define PEX_STRIDE 1156
#define CSTRIDE 858   // u64 per shifted copy
#define WS_IMG8   0
#define WS_BFRAG  1048576
#define WS_PEX    1064960
#define WS_RB     5799936
#define WS_RESULT 9994240
#define WS_CAND   14188544
// within WS_CAND block: cnt@+0, done@+8, tilemax@+1024 (512 f32), cand@+4096

__device__ inline unsigned char f32_to_e4m3(float v) {
    if (!(v > 0.0f)) return 0;
    if (v >= 448.0f) return 0x7e;
    if (v < 0.015625f) {                       // subnormal: m * 2^-9
        int m = (int)(v * 512.0f + 0.5f);
        if (m > 7) return 0x08;
        return (unsigned char)m;
    }
    unsigned int u = __float_as_uint(v) + 0x00080000u;  // round into bit 20
    int e = (int)((u >> 23) & 0xff) - 127;
    int m3 = (int)(u >> 20) & 7;
    int e8 = e + 7;
    if (e8 >= 16) return 0x7e;
    return (unsigned char)((e8 << 3) | m3);
}

// Fused front kernel.
// blocks [0,1024): wrapped row prefix sums + fp8 image emit (row L1-hot)
// blocks [1024,2080): zero d_out
// blocks [2080,2144): A-fragment psf table + zero counters
__global__ void k_pex(const float* __restrict__ img, float* __restrict__ pex,
                      uint32_t* __restrict__ img8, const float* __restrict__ psf,
                      unsigned char* __restrict__ bf, unsigned int* cnt,
                      float4* __restrict__ out, int n4) {
    __shared__ float wtot[4];
    int blk = blockIdx.x, t = threadIdx.x;
    if (blk >= 1024) {
        if (blk < 2080) {
            int i = (blk - 1024) * 256 + t;
            if (i < n4) { float4 z; z.x = z.y = z.z = z.w = 0.f; out[i] = z; }
        } else {
            int u = (blk - 2080) * 256 + t;   // 16384
            if (u == 0) { cnt[0] = 0u; cnt[2] = 0u; }   // cnt, done
            int kb = u >> 9; int l = (u >> 3) & 63; int j = u & 7;
            int z = l & 15; int q = l >> 4;
            int a = kb; int b = q * 8 + j;
            float p = psf[z * 1024 + a * 32 + b];
            float c = cosf((float)(a + b - 32) * (6.283185307179586f / 1024.0f));
            bf[kb * 512 + l * 8 + j] = f32_to_e4m3(p * c * 1024.0f);
        }
        return;
    }
    int r = blk;
    const float* row = img + r * 1024;
    float s[5];
    float acc = 0.f;
    int base = t * 5;
    #pragma unroll
    for (int j = 0; j < 5; j++) {
        int c = base + j;
        float v = (c < 1152) ? row[(c - 64) & 1023] : 0.f;
        acc += v; s[j] = acc;
    }
    float sc = acc;
    int lane = t & 63, w = t >> 6;
    #pragma unroll
    for (int off = 1; off < 64; off <<= 1) {
        float v = __shfl_up(sc, off, 64);
        if (lane >= off) sc += v;
    }
    if (lane == 63) wtot[w] = sc;
    __syncthreads();
    float wbase = 0.f;
    #pragma unroll
    for (int i = 0; i < 3; i++) if (i < w) wbase += wtot[i];
    float excl = wbase + (sc - acc);
    float* prow = pex + r * PEX_STRIDE;
    if (t == 0) prow[0] = 0.f;
    #pragma unroll
    for (int j = 0; j < 5; j++) {
        int c = base + j;
        if (c < 1152) prow[c + 1] = excl + s[j];
    }
    float4 v4 = *(const float4*)(row + 4 * t);
    img8[r * 256 + t] = (uint32_t)f32_to_e4m3(v4.x)
                      | ((uint32_t)f32_to_e4m3(v4.y) << 8)
                      | ((uint32_t)f32_to_e4m3(v4.z) << 16)
                      | ((uint32_t)f32_to_e4m3(v4.w) << 24);
}

// exact disk(r=64) mean via prefix sums, sampled every 16th row; compact output
// rb[s][c] covers rows [16s,16s+16). XCD-banded mapping keeps pex L2-local.
__global__ __launch_bounds__(256) void k_bg(const float* __restrict__ pex,
                                            float* __restrict__ rb) {
    static constexpr int W[64] = {
        63,63,63,63,63,63,63,63,63,63,63,63,
        62,62,62,62, 61,61,61,61, 60,60,60, 59,59, 58,58,58, 57,57, 56,
        55,55, 54,54, 53, 52,52, 51, 50, 49,49,
        48,47,46,45,44,43,42,41,
        39,38,37,35,34,32,30,29,27,24,22,19,15,11
    };
    int blk = blockIdx.x;                 // 128
    int xcd = blk & 7;
    int sub = blk >> 4;                   // 0..7
    int half = (blk >> 3) & 1;
    int s = xcd * 8 + sub;                // sampled-row index 0..63
    int row = s * 16 + 7;
    int n0 = (half << 9) + ((int)threadIdx.x << 1);
    f2u acc0, acc1;
    {
        const float* pr = pex + row * PEX_STRIDE + n0;
        acc0 = *(const f2u*)(pr + 128) - *(const f2u*)(pr + 1);
        acc1 = (f2u)0.f;
    }
    #pragma unroll 3
    for (int dy = 1; dy <= 63; dy++) {
        const int w = W[dy];
        const float* p1 = pex + ((row - dy) & 1023) * PEX_STRIDE + n0;
        const float* p2 = pex + ((row + dy) & 1023) * PEX_STRIDE + n0;
        acc0 += *(const f2u*)(p1 + 65 + w) - *(const f2u*)(p1 + 64 - w);
        acc1 += *(const f2u*)(p2 + 65 + w) - *(const f2u*)(p2 + 64 - w);
    }
    f2u sum = acc0 + acc1;
    const float k = (float)(1.0 / (3.14159265358979323846 * 4096.0));
    f2u r2;
    r2.x = 1.0f / ((sum.x * k + 1.0f) * 1024.0f);   // /1024 undoes psf scale
    r2.y = 1.0f / ((sum.y * k + 1.0f) * 1024.0f);
    *(f2u*)(rb + s * 1024 + n0) = r2;
}

// MFMA conv, swapped operands (A = psf table, M=z; B = image cols from LDS).
// REVERTED to the proven direct-read inner loop (R6 form, fastest measured):
// per kb, 8 paired ds_read2_b64 bursts overlap MFMA across resident waves;
// Toeplitz register pipelines (R7/R8) measurably regress — single outstanding
// LDS refill per iteration cannot hide ds_read latency.
// C: col=lane&15 = image col, row = 4*(lane>>4)+reg = z.
__global__ __launch_bounds__(512, 2) void k_conv(
    const unsigned long long* __restrict__ img64,
    const unsigned long long* __restrict__ bfrag,
    const float* __restrict__ rb, float* __restrict__ result,
    float* __restrict__ tilemax) {
    __shared__ unsigned long long sm[8 * CSTRIDE];   // 54912 B
    __shared__ float bmax[8];
    int tid = threadIdx.x;
    int wave = tid >> 6, lane = tid & 63;
    int b = blockIdx.x;
    int tr = b >> 5, tc = b & 31;
    int r0 = tr * 64, c0 = tc * 32;

    for (int u = tid; u < 665; u += 512) {    // 95 rows x 7 slots
        int dr = u / 7;
        int x8 = u - dr * 7;
        int row = (r0 + dr - 16) & 1023;
        int cb0 = (c0 + x8 * 8 - 16) & 1023;
        int cb1 = (cb0 + 8) & 1023;
        unsigned long long lo = img64[row * 128 + (cb0 >> 3)];
        unsigned long long hi = img64[row * 128 + (cb1 >> 3)];
        int dst = dr * 9 + x8;
        sm[dst] = lo;
        #pragma unroll
        for (int s = 1; s < 8; s++)
            sm[s * CSTRIDE + dst] = (lo >> (8 * s)) | (hi << (64 - 8 * s));
    }
    __syncthreads();

    int i0 = (wave >> 1) * 16;                // tile row group
    int cw = (wave & 1) * 16;                 // col half
    int g = lane >> 4;
    int slot = ((cw + (lane & 15)) >> 3) + g;
    const unsigned long long* bp = sm + (lane & 7) * CSTRIDE + slot + i0 * 9;

    v4f acc[16];
    #pragma unroll
    for (int f = 0; f < 16; f++) acc[f] = (v4f)0.0f;

    unsigned long long anext = bfrag[lane];
    for (int kb = 0; kb < 32; kb++) {
        unsigned long long acur = anext;
        anext = bfrag[((kb < 31 ? kb + 1 : 31) << 6) + lane];
        const unsigned long long* pk = bp + kb * 9;
        #pragma unroll
        for (int cc = 0; cc < 16; cc += 2) {
            unsigned long long b0 = pk[cc * 9];
            unsigned long long b1 = pk[cc * 9 + 9];
            acc[cc]     = __builtin_amdgcn_mfma_f32_16x16x32_fp8_fp8(
                (long)acur, (long)b0, acc[cc], 0, 0, 0);
            acc[cc + 1] = __builtin_amdgcn_mfma_f32_16x16x32_fp8_fp8(
                (long)acur, (long)b1, acc[cc + 1], 0, 0, 0);
        }
    }

    // epilogue: z-max in registers (C rows = z), wave-wide; emit per-tile max
    float zmax[16];
    #pragma unroll
    for (int cc = 0; cc < 16; cc++) {
        v4f v = acc[cc];
        float m = fmaxf(fmaxf(v.x, v.y), fmaxf(v.z, v.w));
        m = fmaxf(m, __shfl_xor(m, 16, 64));
        m = fmaxf(m, __shfl_xor(m, 32, 64));
        zmax[cc] = m;
    }
    int gcol = c0 + cw + (lane & 15);
    float pm = -3.4e38f;
    #pragma unroll
    for (int c4 = 0; c4 < 4; c4++) {
        float m01 = (g & 1) ? zmax[c4 * 4 + 1] : zmax[c4 * 4 + 0];
        float m23 = (g & 1) ? zmax[c4 * 4 + 3] : zmax[c4 * 4 + 2];
        float m = (g & 2) ? m23 : m01;
        int grow = r0 + i0 + c4 * 4 + g;
        float val = m * rb[(grow >> 4) * 1024 + gcol];
        result[grow * 1024 + gcol] = val;
        pm = fmaxf(pm, val);
    }
    #pragma unroll
    for (int d = 1; d < 64; d <<= 1) pm = fmaxf(pm, __shfl_xor(pm, d, 64));
    if (lane == 0) bmax[wave] = pm;
    __syncthreads();
    if (tid == 0) {
        float m = bmax[0];
        #pragma unroll
        for (int i = 1; i < 8; i++) m = fmaxf(m, bmax[i]);
        tilemax[b] = m;
    }
}

// fused maxpool + candidate extraction + (last block) top-k sort & emit.
// Fast reject reads the 2 conv-tile maxes covering this 64x64 region.
__global__ __launch_bounds__(256) void k_maxcand(
    const float* __restrict__ result, const float* __restrict__ tilemax,
    unsigned int* cnt, unsigned long long* cand,
    const float* __restrict__ image, float* __restrict__ out) {
    __shared__ __align__(16) char smbuf[61184];   // ls | hr, aliased keys
    __shared__ unsigned int lastv;
    float* ls = (float*)smbuf;                    // 95*96*4 = 36480
    float* hr = (float*)(smbuf + 36480);          // 95*64*4 = 24320
    unsigned long long* keys = (unsigned long long*)smbuf;  // 16384 (aliased)
    int b = blockIdx.x;                            // 256
    int bx = b & 15, by = b >> 4;
    int i0 = by * 64, j0 = bx * 64;
    int t = threadIdx.x;
    unsigned int* done = cnt + 2;

    float tm = fmaxf(tilemax[by * 32 + 2 * bx], tilemax[by * 32 + 2 * bx + 1]);
    if (tm > 2.0f) {
        // slow path: full separable pooling on the 95x95 halo
        for (int idx = t; idx < 95 * 95; idx += 256) {
            int r = idx / 95, c = idx - r * 95;
            int gr = i0 - 16 + r, gc = j0 - 16 + c;
            float v = -3.4e38f;
            if ((unsigned)gr < 1024u && (unsigned)gc < 1024u) v = result[gr * 1024 + gc];
            ls[r * 96 + c] = v;
        }
        __syncthreads();
        for (int idx = t; idx < 95 * 64; idx += 256) {
            int r = idx >> 6, c = idx & 63;
            const float* p = ls + r * 96 + c;
            float m = p[0];
            #pragma unroll
            for (int d = 1; d < 32; d++) m = fmaxf(m, p[d]);
            hr[idx] = m;
        }
        __syncthreads();
        for (int idx = t; idx < 64 * 64; idx += 256) {
            int r = idx >> 6, c = idx & 63;
            const float* p = hr + r * 64 + c;
            float m = p[0];
            #pragma unroll
            for (int d = 1; d < 32; d++) m = fmaxf(m, p[d * 64]);
            float v = ls[(r + 16) * 96 + (c + 16)];
            int gi = i0 + r, gj = j0 + c;
            if (gi >= 1 && gj >= 1 && v > 2.0f && v == m) {
                unsigned int k = atomicAdd(cnt, 1u);
                if (k < 2048)
                    cand[k] = ((unsigned long long)__float_as_uint(v) << 32)
                            | (unsigned int)(~(unsigned int)(gi * 1024 + gj));
            }
        }
        __syncthreads();
    }

    // last-block election
    __threadfence();
    if (t == 0) lastv = atomicAdd(done, 1u);
    __syncthreads();
    if (lastv != 255) return;
    __threadfence();

    int n = (int)cnt[0]; if (n > 2048) n = 2048;
    if (n == 0) return;                           // d_out already zeroed
    for (int k = t; k < 2048; k += 256) keys[k] = (k < n) ? cand[k] : 0ull;
    __syncthreads();
    for (int size = 2; size <= 2048; size <<= 1) {
        for (int stride = size >> 1; stride > 0; stride >>= 1) {
            for (int i = t; i < 2048; i += 256) {
                int ixj = i ^ stride;
                if (ixj > i) {
                    unsigned long long a = keys[i], bb = keys[ixj];
                    bool sw = ((i & size) == 0) ? (a < bb) : (a > bb);  // descending
                    if (sw) { keys[i] = bb; keys[ixj] = a; }
                }
            }
            __syncthreads();
        }
    }
    float* roipos = out;
    float* intensity = out + 2048;
    float* rois = out + 3072;
    float* validf = out + 3072 + 1048576;
    int nw = n < 1024 ? n : 1024;
    for (int k = t; k < nw; k += 256) {
        unsigned long long key = keys[k];
        float val = __uint_as_float((unsigned int)(key >> 32));
        unsigned int p = ~(unsigned int)key;
        int y = (int)(p >> 10), x = (int)(p & 1023);
        int roy = y - 16, rox = x - 16;
        bool valid = (roy >= 0 && roy < 992 && rox >= 0 && rox < 992);
        int royc = roy < 0 ? 0 : (roy > 992 ? 992 : roy);
        int roxc = rox < 0 ? 0 : (rox > 992 ? 992 : rox);
        roipos[2 * k]     = valid ? (float)royc : 0.f;
        roipos[2 * k + 1] = valid ? (float)roxc : 0.f;
        intensity[k]      = valid ? val : 0.f;
        validf[k]         = valid ? 1.f : 0.f;
    }
    __syncthreads();
    for (int k = 0; k < nw; k++) {
        unsigned long long key = keys[k];
        unsigned int p = ~(unsigned int)key;
        int y = (int)(p >> 10), x = (int)(p & 1023);
        int roy = y - 16, rox = x - 16;
        if (!(roy >= 0 && roy < 992 && rox >= 0 && rox < 992)) continue;
        #pragma unroll
        for (int part = 0; part < 4; part++) {
            int tt = part * 256 + t;
            int u = tt >> 5, vv = tt & 31;
            rois[k * 1024 + tt] = image[(roy + u) * 1024 + (rox + vv)];
        }
    }
}

extern "C" void kernel_launch(void* const* d_in, const int* in_sizes, int n_in,
                              void* d_out, int out_size, void* d_ws, size_t ws_size,
                              hipStream_t stream) {
    const float* image = (const float*)d_in[0];
    const float* psf   = (const float*)d_in[1];
    float* out = (float*)d_out;
    char* ws = (char*)d_ws;
    unsigned char* img8  = (unsigned char*)(ws + WS_IMG8);
    unsigned char* bfrag = (unsigned char*)(ws + WS_BFRAG);
    float* pex = (float*)(ws + WS_PEX);
    float* rb  = (float*)(ws + WS_RB);
    float* result = (float*)(ws + WS_RESULT);
    unsigned int* cnt = (unsigned int*)(ws + WS_CAND);
    float* tilemax = (float*)(ws + WS_CAND + 1024);
    unsigned long long* cand = (unsigned long long*)(ws + WS_CAND + 4096);

    int n4 = out_size / 4;
    hipLaunchKernelGGL(k_pex,     dim3(2144), dim3(256), 0, stream,
                       image, pex, (uint32_t*)img8, psf, bfrag, cnt, (float4*)d_out, n4);
    hipLaunchKernelGGL(k_bg,      dim3(128),  dim3(256), 0, stream, pex, rb);
    hipLaunchKernelGGL(k_conv,    dim3(512),  dim3(512), 0, stream,
                       (const unsigned long long*)img8, (const unsigned long long*)bfrag,
                       rb, result, tilemax);
    hipLaunchKernelGGL(k_maxcand, dim3(256),  dim3(256), 0, stream,
                       result, tilemax, cnt, cand, image, out);
}

// Round 11
// 103.190 us; speedup vs baseline: 1.2021x; 1.1293x over previous
//
#include <hip/hip_runtime.h>
#include <stdint.h>

typedef float v4f __attribute__((ext_vector_type(4)));
typedef float f2u __attribute__((ext_vector_type(2), aligned(4)));  // 4B-aligned float2

#define PEX_STRIDE 1156
#define CSTRIDE 858   // u64 per shifted copy
#define WS_IMG8   0
#define WS_BFRAG  1048576
#define WS_PEX    1064960
#define WS_RB     5799936
#define WS_RESULT 9994240
#define WS_CAND   14188544

__device__ inline unsigned char f32_to_e4m3(float v) {
    if (!(v > 0.0f)) return 0;
    if (v >= 448.0f) return 0x7e;
    if (v < 0.015625f) {                       // subnormal: m * 2^-9
        int m = (int)(v * 512.0f + 0.5f);
        if (m > 7) return 0x08;
        return (unsigned char)m;
    }
    unsigned int u = __float_as_uint(v) + 0x00080000u;  // round into bit 20
    int e = (int)((u >> 23) & 0xff) - 127;
    int m3 = (int)(u >> 20) & 7;
    int e8 = e + 7;
    if (e8 >= 16) return 0x7e;
    return (unsigned char)((e8 << 3) | m3);
}

// Fused front kernel.
// blocks [0,1024): wrapped row prefix sums + fp8 image emit (row L1-hot)
// blocks [1024,2080): zero d_out
// blocks [2080,2144): A-fragment psf table + zero counter
__global__ void k_pex(const float* __restrict__ img, float* __restrict__ pex,
                      uint32_t* __restrict__ img8, const float* __restrict__ psf,
                      unsigned char* __restrict__ bf, unsigned int* cnt,
                      float4* __restrict__ out, int n4) {
    __shared__ float wtot[4];
    int blk = blockIdx.x, t = threadIdx.x;
    if (blk >= 1024) {
        if (blk < 2080) {
            int i = (blk - 1024) * 256 + t;
            if (i < n4) { float4 z; z.x = z.y = z.z = z.w = 0.f; out[i] = z; }
        } else {
            int u = (blk - 2080) * 256 + t;   // 16384
            if (u == 0) cnt[0] = 0u;
            int kb = u >> 9; int l = (u >> 3) & 63; int j = u & 7;
            int z = l & 15; int q = l >> 4;
            int a = kb; int b = q * 8 + j;
            float p = psf[z * 1024 + a * 32 + b];
            float c = cosf((float)(a + b - 32) * (6.283185307179586f / 1024.0f));
            bf[kb * 512 + l * 8 + j] = f32_to_e4m3(p * c * 1024.0f);
        }
        return;
    }
    int r = blk;
    const float* row = img + r * 1024;
    float s[5];
    float acc = 0.f;
    int base = t * 5;
    #pragma unroll
    for (int j = 0; j < 5; j++) {
        int c = base + j;
        float v = (c < 1152) ? row[(c - 64) & 1023] : 0.f;
        acc += v; s[j] = acc;
    }
    float sc = acc;
    int lane = t & 63, w = t >> 6;
    #pragma unroll
    for (int off = 1; off < 64; off <<= 1) {
        float v = __shfl_up(sc, off, 64);
        if (lane >= off) sc += v;
    }
    if (lane == 63) wtot[w] = sc;
    __syncthreads();
    float wbase = 0.f;
    #pragma unroll
    for (int i = 0; i < 3; i++) if (i < w) wbase += wtot[i];
    float excl = wbase + (sc - acc);
    float* prow = pex + r * PEX_STRIDE;
    if (t == 0) prow[0] = 0.f;
    #pragma unroll
    for (int j = 0; j < 5; j++) {
        int c = base + j;
        if (c < 1152) prow[c + 1] = excl + s[j];
    }
    float4 v4 = *(const float4*)(row + 4 * t);
    img8[r * 256 + t] = (uint32_t)f32_to_e4m3(v4.x)
                      | ((uint32_t)f32_to_e4m3(v4.y) << 8)
                      | ((uint32_t)f32_to_e4m3(v4.z) << 16)
                      | ((uint32_t)f32_to_e4m3(v4.w) << 24);
}

// exact disk(r=64) mean via prefix sums, sampled every 16th row; compact output
// rb[s][c] covers rows [16s,16s+16). XCD-banded mapping keeps pex L2-local.
__global__ __launch_bounds__(256) void k_bg(const float* __restrict__ pex,
                                            float* __restrict__ rb) {
    static constexpr int W[64] = {
        63,63,63,63,63,63,63,63,63,63,63,63,
        62,62,62,62, 61,61,61,61, 60,60,60, 59,59, 58,58,58, 57,57, 56,
        55,55, 54,54, 53, 52,52, 51, 50, 49,49,
        48,47,46,45,44,43,42,41,
        39,38,37,35,34,32,30,29,27,24,22,19,15,11
    };
    int blk = blockIdx.x;                 // 128
    int xcd = blk & 7;
    int sub = blk >> 4;                   // 0..7
    int half = (blk >> 3) & 1;
    int s = xcd * 8 + sub;                // sampled-row index 0..63
    int row = s * 16 + 7;
    int n0 = (half << 9) + ((int)threadIdx.x << 1);
    f2u acc0, acc1;
    {
        const float* pr = pex + row * PEX_STRIDE + n0;
        acc0 = *(const f2u*)(pr + 128) - *(const f2u*)(pr + 1);
        acc1 = (f2u)0.f;
    }
    #pragma unroll 3
    for (int dy = 1; dy <= 63; dy++) {
        const int w = W[dy];
        const float* p1 = pex + ((row - dy) & 1023) * PEX_STRIDE + n0;
        const float* p2 = pex + ((row + dy) & 1023) * PEX_STRIDE + n0;
        acc0 += *(const f2u*)(p1 + 65 + w) - *(const f2u*)(p1 + 64 - w);
        acc1 += *(const f2u*)(p2 + 65 + w) - *(const f2u*)(p2 + 64 - w);
    }
    f2u sum = acc0 + acc1;
    const float k = (float)(1.0 / (3.14159265358979323846 * 4096.0));
    f2u r2;
    r2.x = 1.0f / ((sum.x * k + 1.0f) * 1024.0f);   // /1024 undoes psf scale
    r2.y = 1.0f / ((sum.y * k + 1.0f) * 1024.0f);
    *(f2u*)(rb + s * 1024 + n0) = r2;
}

// MFMA conv, swapped operands: A = psf table (M=z), B = image fragment from
// LDS shifted copies. C: col=lane&15 = image col, row = 4*(lane>>4)+reg = z.
// Direct paired ds_read inner loop — the measured-best form (102.6 µs config).
// __launch_bounds__(512,4) caps VGPR at 128 => guaranteed 2 blocks/CU
// (the tilemax-epilogue variants exceeded 128 and halved occupancy: 116-124 µs).
__global__ __launch_bounds__(512, 4) void k_conv(
    const unsigned long long* __restrict__ img64,
    const unsigned long long* __restrict__ bfrag,
    const float* __restrict__ rb, float* __restrict__ result) {
    __shared__ unsigned long long sm[8 * CSTRIDE];   // 54912 B
    int tid = threadIdx.x;
    int wave = tid >> 6, lane = tid & 63;
    int b = blockIdx.x;
    int tr = b >> 5, tc = b & 31;
    int r0 = tr * 64, c0 = tc * 32;

    for (int u = tid; u < 665; u += 512) {    // 95 rows x 7 slots
        int dr = u / 7;
        int x8 = u - dr * 7;
        int row = (r0 + dr - 16) & 1023;
        int cb0 = (c0 + x8 * 8 - 16) & 1023;
        int cb1 = (cb0 + 8) & 1023;
        unsigned long long lo = img64[row * 128 + (cb0 >> 3)];
        unsigned long long hi = img64[row * 128 + (cb1 >> 3)];
        int dst = dr * 9 + x8;
        sm[dst] = lo;
        #pragma unroll
        for (int s = 1; s < 8; s++)
            sm[s * CSTRIDE + dst] = (lo >> (8 * s)) | (hi << (64 - 8 * s));
    }
    __syncthreads();

    int i0 = (wave >> 1) * 16;                // tile row group
    int cw = (wave & 1) * 16;                 // col half
    int g = lane >> 4;
    int slot = ((cw + (lane & 15)) >> 3) + g;
    const unsigned long long* bp = sm + (lane & 7) * CSTRIDE + slot + i0 * 9;

    v4f acc[16];
    #pragma unroll
    for (int f = 0; f < 16; f++) acc[f] = (v4f)0.0f;

    unsigned long long anext = bfrag[lane];
    for (int kb = 0; kb < 32; kb++) {
        unsigned long long acur = anext;
        anext = bfrag[((kb < 31 ? kb + 1 : 31) << 6) + lane];
        const unsigned long long* pk = bp + kb * 9;
        #pragma unroll
        for (int cc = 0; cc < 16; cc += 2) {
            unsigned long long b0 = pk[cc * 9];
            unsigned long long b1 = pk[cc * 9 + 9];
            acc[cc]     = __builtin_amdgcn_mfma_f32_16x16x32_fp8_fp8(
                (long)acur, (long)b0, acc[cc], 0, 0, 0);
            acc[cc + 1] = __builtin_amdgcn_mfma_f32_16x16x32_fp8_fp8(
                (long)acur, (long)b1, acc[cc + 1], 0, 0, 0);
        }
    }

    // epilogue: z-max in registers (C rows = z), wave-wide, store ratio
    float zmax[16];
    #pragma unroll
    for (int cc = 0; cc < 16; cc++) {
        v4f v = acc[cc];
        float m = fmaxf(fmaxf(v.x, v.y), fmaxf(v.z, v.w));
        m = fmaxf(m, __shfl_xor(m, 16, 64));
        m = fmaxf(m, __shfl_xor(m, 32, 64));
        zmax[cc] = m;
    }
    int gcol = c0 + cw + (lane & 15);
    #pragma unroll
    for (int c4 = 0; c4 < 4; c4++) {
        float m01 = (g & 1) ? zmax[c4 * 4 + 1] : zmax[c4 * 4 + 0];
        float m23 = (g & 1) ? zmax[c4 * 4 + 3] : zmax[c4 * 4 + 2];
        float m = (g & 2) ? m23 : m01;
        int grow = r0 + i0 + c4 * 4 + g;
        result[grow * 1024 + gcol] = m * rb[(grow >> 4) * 1024 + gcol];
    }
}

// fused 32x32 stride-1 maxpool + candidate extraction, with fast reject.
__global__ __launch_bounds__(256) void k_maxcand(const float* __restrict__ result,
                                                 unsigned int* cnt,
                                                 unsigned long long* cand) {
    __shared__ float ls[95 * 96];
    __shared__ float hr[95 * 64];
    __shared__ float wmax[4];
    int bx = blockIdx.x & 15, by = blockIdx.x >> 4;
    int i0 = by * 64, j0 = bx * 64;
    int t = threadIdx.x;
    // fast reject: tile max over the 64x64 core (float4 loads)
    const float4* cb4 = (const float4*)(result + i0 * 1024 + j0);
    float mx = -3.4e38f;
    #pragma unroll
    for (int k = 0; k < 4; k++) {
        int idx = k * 256 + t;                 // 1024 float4: row idx>>4, col4 idx&15
        float4 v = cb4[(idx >> 4) * 256 + (idx & 15)];
        mx = fmaxf(mx, fmaxf(fmaxf(v.x, v.y), fmaxf(v.z, v.w)));
    }
    #pragma unroll
    for (int m = 1; m < 64; m <<= 1) mx = fmaxf(mx, __shfl_xor(mx, m, 64));
    if ((t & 63) == 0) wmax[t >> 6] = mx;
    __syncthreads();
    float tmax = fmaxf(fmaxf(wmax[0], wmax[1]), fmaxf(wmax[2], wmax[3]));
    if (tmax <= 2.0f) return;

    // slow path: full separable pooling on the 95x95 halo
    for (int idx = t; idx < 95 * 95; idx += 256) {
        int r = idx / 95, c = idx - r * 95;
        int gr = i0 - 16 + r, gc = j0 - 16 + c;
        float v = -3.4e38f;
        if ((unsigned)gr < 1024u && (unsigned)gc < 1024u) v = result[gr * 1024 + gc];
        ls[r * 96 + c] = v;
    }
    __syncthreads();
    for (int idx = t; idx < 95 * 64; idx += 256) {
        int r = idx >> 6, c = idx & 63;
        const float* p = ls + r * 96 + c;
        float m = p[0];
        #pragma unroll
        for (int d = 1; d < 32; d++) m = fmaxf(m, p[d]);
        hr[idx] = m;
    }
    __syncthreads();
    for (int idx = t; idx < 64 * 64; idx += 256) {
        int r = idx >> 6, c = idx & 63;
        const float* p = hr + r * 64 + c;
        float m = p[0];
        #pragma unroll
        for (int d = 1; d < 32; d++) m = fmaxf(m, p[d * 64]);
        float v = ls[(r + 16) * 96 + (c + 16)];
        int gi = i0 + r, gj = j0 + c;
        if (gi >= 1 && gj >= 1 && v > 2.0f && v == m) {
            unsigned int k = atomicAdd(cnt, 1u);
            if (k < 2048)
                cand[k] = ((unsigned long long)__float_as_uint(v) << 32)
                        | (unsigned int)(~(unsigned int)(gi * 1024 + gj));
        }
    }
}

// sort candidates (value desc, index asc) and emit outputs; empty fast path
__global__ __launch_bounds__(1024) void k_final(
    const float* __restrict__ image, const unsigned int* __restrict__ cnt,
    const unsigned long long* __restrict__ cand, float* __restrict__ out) {
    __shared__ unsigned long long keys[2048];
    int t = threadIdx.x;
    int n = (int)cnt[0]; if (n > 2048) n = 2048;
    if (n == 0) return;                         // d_out already zeroed by k_pex
    for (int k = t; k < 2048; k += 1024) keys[k] = (k < n) ? cand[k] : 0ull;
    __syncthreads();
    for (int size = 2; size <= 2048; size <<= 1) {
        for (int stride = size >> 1; stride > 0; stride >>= 1) {
            for (int i = t; i < 2048; i += 1024) {
                int ixj = i ^ stride;
                if (ixj > i) {
                    unsigned long long a = keys[i], b = keys[ixj];
                    bool sw = ((i & size) == 0) ? (a < b) : (a > b);  // descending
                    if (sw) { keys[i] = b; keys[ixj] = a; }
                }
            }
            __syncthreads();
        }
    }
    float* roipos = out;
    float* intensity = out + 2048;
    float* rois = out + 3072;
    float* validf = out + 3072 + 1048576;
    int nw = n < 1024 ? n : 1024;
    if (t < nw) {
        unsigned long long key = keys[t];
        float val = __uint_as_float((unsigned int)(key >> 32));
        unsigned int p = ~(unsigned int)key;
        int y = (int)(p >> 10), x = (int)(p & 1023);
        int roy = y - 16, rox = x - 16;
        bool valid = (roy >= 0 && roy < 992 && rox >= 0 && rox < 992);
        int royc = roy < 0 ? 0 : (roy > 992 ? 992 : roy);
        int roxc = rox < 0 ? 0 : (rox > 992 ? 992 : rox);
        roipos[2 * t]     = valid ? (float)royc : 0.f;
        roipos[2 * t + 1] = valid ? (float)roxc : 0.f;
        intensity[t]      = valid ? val : 0.f;
        validf[t]         = valid ? 1.f : 0.f;
    }
    __syncthreads();
    for (int k = 0; k < nw; k++) {
        unsigned long long key = keys[k];
        unsigned int p = ~(unsigned int)key;
        int y = (int)(p >> 10), x = (int)(p & 1023);
        int roy = y - 16, rox = x - 16;
        if (!(roy >= 0 && roy < 992 && rox >= 0 && rox < 992)) continue;
        int u = t >> 5, vv = t & 31;
        rois[k * 1024 + t] = image[(roy + u) * 1024 + (rox + vv)];
    }
}

extern "C" void kernel_launch(void* const* d_in, const int* in_sizes, int n_in,
                              void* d_out, int out_size, void* d_ws, size_t ws_size,
                              hipStream_t stream) {
    const float* image = (const float*)d_in[0];
    const float* psf   = (const float*)d_in[1];
    float* out = (float*)d_out;
    char* ws = (char*)d_ws;
    unsigned char* img8  = (unsigned char*)(ws + WS_IMG8);
    unsigned char* bfrag = (unsigned char*)(ws + WS_BFRAG);
    float* pex = (float*)(ws + WS_PEX);
    float* rb  = (float*)(ws + WS_RB);
    float* result = (float*)(ws + WS_RESULT);
    unsigned int* cnt = (unsigned int*)(ws + WS_CAND);
    unsigned long long* cand = (unsigned long long*)(ws + WS_CAND + 16);

    int n4 = out_size / 4;
    hipLaunchKernelGGL(k_pex,     dim3(2144), dim3(256), 0, stream,
                       image, pex, (uint32_t*)img8, psf, bfrag, cnt, (float4*)d_out, n4);
    hipLaunchKernelGGL(k_bg,      dim3(128),  dim3(256), 0, stream, pex, rb);
    hipLaunchKernelGGL(k_conv,    dim3(512),  dim3(512), 0, stream,
                       (const unsigned long long*)img8, (const unsigned long long*)bfrag,
                       rb, result);
    hipLaunchKernelGGL(k_maxcand, dim3(256),  dim3(256), 0, stream, result, cnt, cand);
    hipLaunchKernelGGL(k_final,   dim3(1),    dim3(1024), 0, stream, image, cnt, cand, out);
}